// Round 2
// baseline (2214.193 us; speedup 1.0000x reference)
//
#include <hip/hip_runtime.h>

typedef _Float16 f16;
typedef _Float16 f16x8 __attribute__((ext_vector_type(8)));
typedef float f32x4 __attribute__((ext_vector_type(4)));

#define BM 256
#define BN 256
#define BK 32

// async global->LDS, 16B per lane; LDS dest must be linear (base + lane*16).
__device__ __forceinline__ void gload_lds16(const void* g, void* l) {
  __builtin_amdgcn_global_load_lds(
      (const __attribute__((address_space(1))) void*)g,
      (__attribute__((address_space(3))) void*)l, 16, 0, 0);
}

__device__ __forceinline__ float act_apply(float x, int id) {
  switch (id) {
    case 0: return fmaxf(x, 0.0f);
    case 1: return 1.0f / (1.0f + __expf(-x));
    case 2: return tanhf(x);
    case 3: return x >= 0.0f ? x : 0.1f * x;
    default: return 1.0507009873554805f *
                    (x > 0.0f ? x : 1.6732632423543772f * expm1f(x));
  }
}

// C = act(A @ W^T * Sa + bias) * invSn
// A: M x K (fp16, scaled), W: N x K (fp16), out: M x N (fp16 or fp32 for FINAL)
// 256x256 tile, BK=32, 4-deep LDS ring, counted vmcnt, swizzled LDS.
template <bool FINAL>
__global__ __launch_bounds__(512, 2)
void gemm_bias_act(const f16* __restrict__ A, const f16* __restrict__ W,
                   const float* __restrict__ bias, const int* __restrict__ ids,
                   float Sa, float invSn, void* __restrict__ outv,
                   int M, int N, int K) {
  __shared__ f16 lA[4][BM * BK];   // 4 x 16 KiB
  __shared__ f16 lB[4][BN * BK];   // 4 x 16 KiB  (total 128 KiB)

  const int tid  = (int)threadIdx.x;
  const int lane = tid & 63;
  const int wid  = tid >> 6;   // 0..7
  const int wm   = wid >> 2;   // 0..1 : row half (128 rows)
  const int wn   = wid & 3;    // 0..3 : col quarter (64 cols)

  // bijective XCD-aware swizzle (nwg % 8 == 0 for all shapes here)
  const int nbx = N >> 8;
  const int nwg = (M >> 8) * nbx;
  const int b   = (int)blockIdx.x;
  const int swz = (b & 7) * (nwg >> 3) + (b >> 3);
  const int brow = (swz / nbx) << 8;
  const int bcol = (swz % nbx) << 8;

  // ---- staging: pre-swizzled global source, linear LDS dest ----
  // sigma(x) = x ^ (((x>>7)&7)<<4)  (involution; flips bits 4-6 from row bits 1-3)
  const int d0 = tid << 4;            // dest byte 0..8191
  const int d1 = d0 + 8192;           // dest byte 8192..16383
  const int s0 = d0 ^ (((d0 >> 7) & 7) << 4);
  const int s1 = d1 ^ (((d1 >> 7) & 7) << 4);
  const int r0 = s0 >> 6, c0 = (s0 >> 4) & 3;   // source row, 16B-block in K
  const int r1 = s1 >> 6, c1 = (s1 >> 4) & 3;

  const f16* pA0 = A + (long)(brow + r0) * K + c0 * 8;
  const f16* pA1 = A + (long)(brow + r1) * K + c1 * 8;
  const f16* pB0 = W + (long)(bcol + r0) * K + c0 * 8;
  const f16* pB1 = W + (long)(bcol + r1) * K + c1 * 8;
  const int e0 = tid << 3;            // LDS dest in elements
  const int e1 = e0 + 4096;

#define STAGE(t)                                    \
  do {                                              \
    const int _s = (t) & 3;                         \
    const long _k = (long)(t) << 5;                 \
    gload_lds16(pA0 + _k, &lA[_s][e0]);             \
    gload_lds16(pA1 + _k, &lA[_s][e1]);             \
    gload_lds16(pB0 + _k, &lB[_s][e0]);             \
    gload_lds16(pB1 + _k, &lB[_s][e1]);             \
  } while (0)

  // ---- fragment read addressing (swizzled) ----
  const int fr = lane & 15;
  const int kb = lane >> 4;                 // 0..3 : which 16B block of K=32
  const int xorv = ((fr >> 1) & 7) << 4;    // lane-constant across fragments
  const char* baA = (const char*)&lA[0][0];
  const char* baB = (const char*)&lB[0][0];

  int offA[8], offB[4];
#pragma unroll
  for (int m = 0; m < 8; ++m)
    offA[m] = (((wm * 128 + m * 16 + fr) << 6) + (kb << 4)) ^ xorv;
#pragma unroll
  for (int n = 0; n < 4; ++n)
    offB[n] = (((wn * 64 + n * 16 + fr) << 6) + (kb << 4)) ^ xorv;

  f32x4 acc[8][4];
#pragma unroll
  for (int m = 0; m < 8; ++m)
#pragma unroll
    for (int n = 0; n < 4; ++n) acc[m][n] = (f32x4){0.f, 0.f, 0.f, 0.f};

  const int nt = K >> 5;   // 64 or 128

  // prologue: 3 tiles in flight
  STAGE(0);
  STAGE(1);
  STAGE(2);

  for (int i = 0; i < nt; ++i) {
    // issue prefetch for tile i+3, then wait so that tile i is fully landed.
    if (i + 3 < nt) {
      STAGE(i + 3);
      asm volatile("s_waitcnt vmcnt(12)" ::: "memory");
    } else if (nt - 1 - i == 2) {
      asm volatile("s_waitcnt vmcnt(8)" ::: "memory");
    } else if (nt - 1 - i == 1) {
      asm volatile("s_waitcnt vmcnt(4)" ::: "memory");
    } else {
      asm volatile("s_waitcnt vmcnt(0)" ::: "memory");
    }
    __builtin_amdgcn_s_barrier();
    asm volatile("" ::: "memory");

    const int so = (i & 3) << 14;   // slot byte offset
    f16x8 af[8], bf[4];
#pragma unroll
    for (int m = 0; m < 8; ++m)
      af[m] = *(const f16x8*)(baA + so + offA[m]);
#pragma unroll
    for (int n = 0; n < 4; ++n)
      bf[n] = *(const f16x8*)(baB + so + offB[n]);

    __builtin_amdgcn_s_setprio(1);
#pragma unroll
    for (int m = 0; m < 8; ++m)
#pragma unroll
      for (int n = 0; n < 4; ++n)
        acc[m][n] = __builtin_amdgcn_mfma_f32_16x16x32_f16(af[m], bf[n],
                                                           acc[m][n], 0, 0, 0);
    __builtin_amdgcn_s_setprio(0);

    asm volatile("" ::: "memory");
    __builtin_amdgcn_s_barrier();
  }
#undef STAGE

  // D layout: row = (lane>>4)*4 + reg, col = lane&15  (m89-verified)
  const int r4 = (lane >> 4) << 2;
#pragma unroll
  for (int n = 0; n < 4; ++n) {
    const int gcol = bcol + wn * 64 + n * 16 + fr;
    const float bv = bias[gcol];
    const int id   = ids[gcol];
#pragma unroll
    for (int m = 0; m < 8; ++m) {
      const int grow = brow + wm * 128 + m * 16 + r4;
#pragma unroll
      for (int i = 0; i < 4; ++i) {
        const float y = act_apply(acc[m][n][i] * Sa + bv, id);
        if (FINAL) {
          ((float*)outv)[(long)(grow + i) * N + gcol] = y;
        } else {
          ((f16*)outv)[(long)(grow + i) * N + gcol] = (f16)(y * invSn);
        }
      }
    }
  }
}

__global__ void cvt_f32_to_f16(const float* __restrict__ in, f16* __restrict__ out,
                               float scale, int n) {
  int i = ((int)blockIdx.x * 256 + (int)threadIdx.x) * 8;
  const int stride = (int)gridDim.x * 256 * 8;
  for (; i < n; i += stride) {
    const float4 v0 = *(const float4*)(in + i);
    const float4 v1 = *(const float4*)(in + i + 4);
    f16x8 h;
    h[0] = (f16)(v0.x * scale); h[1] = (f16)(v0.y * scale);
    h[2] = (f16)(v0.z * scale); h[3] = (f16)(v0.w * scale);
    h[4] = (f16)(v1.x * scale); h[5] = (f16)(v1.y * scale);
    h[6] = (f16)(v1.z * scale); h[7] = (f16)(v1.w * scale);
    *(f16x8*)(out + i) = h;
  }
}

extern "C" void kernel_launch(void* const* d_in, const int* in_sizes, int n_in,
                              void* d_out, int out_size, void* d_ws, size_t ws_size,
                              hipStream_t stream) {
  (void)in_sizes; (void)n_in; (void)out_size; (void)ws_size;
  const int M = 8192, IND = 2048, HID = 4096, OUTD = 2048;
  const float* x = (const float*)d_in[0];

  // workspace: actA (8192*4096 f16) | actB (8192*4096 f16) | wbuf (4096*4096 f16)
  f16* actA = (f16*)d_ws;
  f16* actB = actA + (size_t)M * HID;
  f16* wbuf = actB + (size_t)M * HID;

  // static per-layer activation scales (powers of 2, exact): h_i stored as h/S[i]
  const float S[6] = {1.f, 16.f, 512.f, 16384.f, 262144.f, 8388608.f};

  const int Ks[6] = {IND, HID, HID, HID, HID, HID};
  const int Ns[6] = {HID, HID, HID, HID, HID, OUTD};

  cvt_f32_to_f16<<<2048, 256, 0, stream>>>(x, actA, 1.0f, M * IND);

  f16* cur = actA;
  f16* nxt = actB;
  for (int i = 0; i < 6; ++i) {
    const int K = Ks[i], N = Ns[i];
    const float* w  = (const float*)d_in[1 + 3 * i];
    const float* bs = (const float*)d_in[2 + 3 * i];
    const int* id   = (const int*)d_in[3 + 3 * i];

    cvt_f32_to_f16<<<2048, 256, 0, stream>>>(w, wbuf, 1.0f, N * K);

    const int nblk = (M >> 8) * (N >> 8);
    if (i < 5) {
      gemm_bias_act<false><<<nblk, 512, 0, stream>>>(
          cur, wbuf, bs, id, S[i], 1.0f / S[i + 1], nxt, M, N, K);
      f16* t = cur; cur = nxt; nxt = t;
    } else {
      gemm_bias_act<true><<<nblk, 512, 0, stream>>>(
          cur, wbuf, bs, id, S[i], 1.0f, d_out, M, N, K);
    }
  }
}

// Round 3
// 1951.483 us; speedup vs baseline: 1.1346x; 1.1346x over previous
//
#include <hip/hip_runtime.h>

typedef _Float16 f16;
typedef _Float16 f16x8 __attribute__((ext_vector_type(8)));
typedef float f32x4 __attribute__((ext_vector_type(4)));

// async global->LDS, 16B per lane; LDS dest must be linear (base + lane*16).
__device__ __forceinline__ void gload_lds16(const void* g, void* l) {
  __builtin_amdgcn_global_load_lds(
      (const __attribute__((address_space(1))) void*)g,
      (__attribute__((address_space(3))) void*)l, 16, 0, 0);
}

__device__ __forceinline__ float act_apply(float x, int id) {
  switch (id) {
    case 0: return fmaxf(x, 0.0f);
    case 1: return 1.0f / (1.0f + __expf(-x));
    case 2: return tanhf(x);
    case 3: return x >= 0.0f ? x : 0.1f * x;
    default: return 1.0507009873554805f *
                    (x > 0.0f ? x : 1.6732632423543772f * expm1f(x));
  }
}

// C = act(A @ W^T * Sa + bias) * invSn
// 256x256 tile, BK=32, 4-slot LDS ring, 2-phase interleaved pipeline,
// counted vmcnt (6/4/0), reg-frag one-phase-ahead, swizzled LDS (0 conflicts).
template <bool FINAL>
__global__ __launch_bounds__(512, 2)
void gemm_bias_act(const f16* __restrict__ A, const f16* __restrict__ W,
                   const float* __restrict__ bias, const int* __restrict__ ids,
                   float Sa, float invSn, void* __restrict__ outv,
                   int M, int N, int K) {
  __shared__ f16 lA[4][256 * 32];   // 4 x 16 KiB
  __shared__ f16 lB[4][256 * 32];   // 4 x 16 KiB  (total 128 KiB)

  const int tid  = (int)threadIdx.x;
  const int lane = tid & 63;
  const int wid  = tid >> 6;   // 0..7
  const int wm   = wid >> 2;   // 0..1 : row half (128 rows)
  const int wn   = wid & 3;    // 0..3 : col quarter (64 cols)

  // bijective XCD-aware swizzle (nwg % 8 == 0 for all shapes here)
  const int nbx = N >> 8;
  const int nwg = (M >> 8) * nbx;
  const int b   = (int)blockIdx.x;
  const int swz = (b & 7) * (nwg >> 3) + (b >> 3);
  const int brow = (swz / nbx) << 8;
  const int bcol = (swz % nbx) << 8;

  // ---- staging: pre-swizzled global source, linear LDS dest (validated r2) ----
  const int d0 = tid << 4;            // dest byte 0..8191
  const int d1 = d0 + 8192;           // dest byte 8192..16383
  const int s0 = d0 ^ (((d0 >> 7) & 7) << 4);
  const int s1 = d1 ^ (((d1 >> 7) & 7) << 4);
  const int r0 = s0 >> 6, c0 = (s0 >> 4) & 3;   // source row, 16B-block in K
  const int r1 = s1 >> 6, c1 = (s1 >> 4) & 3;

  const f16* pA0 = A + (long)(brow + r0) * K + c0 * 8;
  const f16* pA1 = A + (long)(brow + r1) * K + c1 * 8;
  const f16* pB0 = W + (long)(bcol + r0) * K + c0 * 8;
  const f16* pB1 = W + (long)(bcol + r1) * K + c1 * 8;
  const int e0 = tid << 3;            // LDS dest in elements
  const int e1 = e0 + 4096;

  // ---- fragment read addressing (swizzled, validated r2) ----
  const int fr = lane & 15;
  const int kb = lane >> 4;
  const int xorv = ((fr >> 1) & 7) << 4;
  const char* baA = (const char*)&lA[0][0];
  const char* baB = (const char*)&lB[0][0];

  int offA[8], offB[4];
#pragma unroll
  for (int m = 0; m < 8; ++m)
    offA[m] = (((wm * 128 + m * 16 + fr) << 6) + (kb << 4)) ^ xorv;
#pragma unroll
  for (int n = 0; n < 4; ++n)
    offB[n] = (((wn * 64 + n * 16 + fr) << 6) + (kb << 4)) ^ xorv;

  f32x4 acc[8][4];
#pragma unroll
  for (int m = 0; m < 8; ++m)
#pragma unroll
    for (int n = 0; n < 4; ++n) acc[m][n] = (f32x4){0.f, 0.f, 0.f, 0.f};

  const int nt = K >> 5;   // 64 or 128

  // prologue: 3 tiles fully staged; per-thread issue order is monotone in t
#pragma unroll
  for (int t = 0; t < 3; ++t) {
    const long kk = (long)t << 5;
    gload_lds16(pA0 + kk, &lA[t][e0]);
    gload_lds16(pA1 + kk, &lA[t][e1]);
    gload_lds16(pB0 + kk, &lB[t][e0]);
    gload_lds16(pB1 + kk, &lB[t][e1]);
  }
  asm volatile("s_waitcnt vmcnt(8)" ::: "memory");  // tile 0 landed (this wave)
  __builtin_amdgcn_s_barrier();                     // ... and all waves
  asm volatile("" ::: "memory");

  // preload tile-0 fragments: A(m0-3), B(n0-3)
  f16x8 afA[4], afB[4], bf[4];
#pragma unroll
  for (int m = 0; m < 4; ++m) afA[m] = *(const f16x8*)(baA + offA[m]);
#pragma unroll
  for (int n = 0; n < 4; ++n) bf[n]  = *(const f16x8*)(baB + offB[n]);

  for (int i = 0; i < nt; ++i) {
    const int so  = (i & 3) << 14;          // current slot byte offset
    const int so2 = ((i + 1) & 3) << 14;    // next slot
    const int ps  = (i + 3) & 3;            // prefetch slot (= (i-1)&3)
    const long kk3 = (long)(i + 3) << 5;
    const bool pf = (i + 3) < nt;

    // ---------- phase A: ds_read(A m4-7) || gload h1 || MFMA(m0-3) ----------
#pragma unroll
    for (int m = 0; m < 4; ++m)
      afB[m] = *(const f16x8*)(baA + so + offA[m + 4]);
    if (pf) {
      gload_lds16(pA0 + kk3, &lA[ps][e0]);
      gload_lds16(pB0 + kk3, &lB[ps][e0]);
    }
    __builtin_amdgcn_s_setprio(1);
#pragma unroll
    for (int m = 0; m < 4; ++m)
#pragma unroll
      for (int n = 0; n < 4; ++n)
        acc[m][n] = __builtin_amdgcn_mfma_f32_16x16x32_f16(afA[m], bf[n],
                                                           acc[m][n], 0, 0, 0);
    __builtin_amdgcn_s_setprio(0);
    asm volatile("" ::: "memory");
    __builtin_amdgcn_s_barrier();           // B1
    asm volatile("" ::: "memory");

    // ---------- phase B: vmcnt+bar -> MFMA(m4-7) || next-tile frags || h2 ----
    if (i < nt - 1) {
      // tile i+1 must be fully in LDS (all waves) before reading slot so2.
      // in flight allowed: tile i+2 (4 loads) + h1 of tile i+3 (2 loads) = 6.
      if (i < nt - 3)       asm volatile("s_waitcnt vmcnt(6)" ::: "memory");
      else if (i == nt - 3) asm volatile("s_waitcnt vmcnt(4)" ::: "memory");
      else                  asm volatile("s_waitcnt vmcnt(0)" ::: "memory");
      __builtin_amdgcn_s_barrier();         // B2'
      asm volatile("" ::: "memory");
    }
    __builtin_amdgcn_s_setprio(1);
#pragma unroll
    for (int m = 0; m < 4; ++m)
#pragma unroll
      for (int n = 0; n < 4; ++n)
        acc[4 + m][n] = __builtin_amdgcn_mfma_f32_16x16x32_f16(afB[m], bf[n],
                                                               acc[4 + m][n],
                                                               0, 0, 0);
    __builtin_amdgcn_s_setprio(0);
    if (i < nt - 1) {
      // load next tile's A(m0-3), B(n0-3) fragments (consumed in next phase A)
#pragma unroll
      for (int m = 0; m < 4; ++m)
        afA[m] = *(const f16x8*)(baA + so2 + offA[m]);
#pragma unroll
      for (int n = 0; n < 4; ++n)
        bf[n] = *(const f16x8*)(baB + so2 + offB[n]);
      if (pf) {
        gload_lds16(pA1 + kk3, &lA[ps][e1]);
        gload_lds16(pB1 + kk3, &lB[ps][e1]);
      }
      asm volatile("" ::: "memory");
      __builtin_amdgcn_s_barrier();         // B2
      asm volatile("" ::: "memory");
    }
  }

  // D layout: row = (lane>>4)*4 + reg, col = lane&15  (m89-verified)
  const int r4 = (lane >> 4) << 2;
#pragma unroll
  for (int n = 0; n < 4; ++n) {
    const int gcol = bcol + wn * 64 + n * 16 + fr;
    const float bv = bias[gcol];
    const int id   = ids[gcol];
#pragma unroll
    for (int m = 0; m < 8; ++m) {
      const int grow = brow + wm * 128 + m * 16 + r4;
#pragma unroll
      for (int i = 0; i < 4; ++i) {
        const float y = act_apply(acc[m][n][i] * Sa + bv, id);
        if (FINAL) {
          ((float*)outv)[(long)(grow + i) * N + gcol] = y;
        } else {
          ((f16*)outv)[(long)(grow + i) * N + gcol] = (f16)(y * invSn);
        }
      }
    }
  }
}

__global__ void cvt_f32_to_f16(const float* __restrict__ in, f16* __restrict__ out,
                               float scale, int n) {
  int i = ((int)blockIdx.x * 256 + (int)threadIdx.x) * 8;
  const int stride = (int)gridDim.x * 256 * 8;
  for (; i < n; i += stride) {
    const float4 v0 = *(const float4*)(in + i);
    const float4 v1 = *(const float4*)(in + i + 4);
    f16x8 h;
    h[0] = (f16)(v0.x * scale); h[1] = (f16)(v0.y * scale);
    h[2] = (f16)(v0.z * scale); h[3] = (f16)(v0.w * scale);
    h[4] = (f16)(v1.x * scale); h[5] = (f16)(v1.y * scale);
    h[6] = (f16)(v1.z * scale); h[7] = (f16)(v1.w * scale);
    *(f16x8*)(out + i) = h;
  }
}

extern "C" void kernel_launch(void* const* d_in, const int* in_sizes, int n_in,
                              void* d_out, int out_size, void* d_ws, size_t ws_size,
                              hipStream_t stream) {
  (void)in_sizes; (void)n_in; (void)out_size; (void)ws_size;
  const int M = 8192, IND = 2048, HID = 4096, OUTD = 2048;
  const float* x = (const float*)d_in[0];

  // workspace: actA (8192*4096 f16) | actB (8192*4096 f16) | wbuf (4096*4096 f16)
  f16* actA = (f16*)d_ws;
  f16* actB = actA + (size_t)M * HID;
  f16* wbuf = actB + (size_t)M * HID;

  // static per-layer activation scales (powers of 2, exact): h_i stored as h/S[i]
  const float S[6] = {1.f, 16.f, 512.f, 16384.f, 262144.f, 8388608.f};

  const int Ks[6] = {IND, HID, HID, HID, HID, HID};
  const int Ns[6] = {HID, HID, HID, HID, HID, OUTD};

  cvt_f32_to_f16<<<2048, 256, 0, stream>>>(x, actA, 1.0f, M * IND);

  f16* cur = actA;
  f16* nxt = actB;
  for (int i = 0; i < 6; ++i) {
    const int K = Ks[i], N = Ns[i];
    const float* w  = (const float*)d_in[1 + 3 * i];
    const float* bs = (const float*)d_in[2 + 3 * i];
    const int* id   = (const int*)d_in[3 + 3 * i];

    cvt_f32_to_f16<<<2048, 256, 0, stream>>>(w, wbuf, 1.0f, N * K);

    const int nblk = (M >> 8) * (N >> 8);
    if (i < 5) {
      gemm_bias_act<false><<<nblk, 512, 0, stream>>>(
          cur, wbuf, bs, id, S[i], 1.0f / S[i + 1], nxt, M, N, K);
      f16* t = cur; cur = nxt; nxt = t;
    } else {
      gemm_bias_act<true><<<nblk, 512, 0, stream>>>(
          cur, wbuf, bs, id, S[i], 1.0f, d_out, M, N, K);
    }
  }
}